// Round 1
// baseline (119.009 us; speedup 1.0000x reference)
//
#include <hip/hip_runtime.h>

#define HW (512 * 512)

typedef float vfloat4 __attribute__((ext_vector_type(4)));  // clang-native: OK for nontemporal builtins

constexpr int TX = 64, TY = 32;       // pixel tile per block; 256 threads x two (4x1 px) strips
constexpr int CWP = 67;               // LDS row stride for 66-wide halo tile (+1 pad)
constexpr float BWIDTH = 1.0f / 15.0f;
constexpr float DELTA = 3e-5f;        // guard >= ~2.5x the 1.2e-5 fast-path error bound

__global__ __launch_bounds__(256) void nectar_binning_kernel(
    const float* __restrict__ logits,      // [16,4,512,512]
    const float* __restrict__ val_freqs,   // [4,9,15]
    float* __restrict__ out)               // [16,4,512,512]
{
    // one-hot nibble pack per halo cell: 1u<<(4*class), 0 for out-of-bounds
    __shared__ unsigned int cls[34 * CWP];   // 34 rows (32 + 2 halo) x 67
    __shared__ float vf[540];

    const int b  = blockIdx.z;
    const int w0 = blockIdx.x * TX;
    const int h0 = blockIdx.y * TY;
    const int tid = threadIdx.x;

    for (int i = tid; i < 540; i += 256) vf[i] = val_freqs[i];

    const float* lb = logits + (size_t)b * 4 * HW;

    const int tix = tid & 15;          // strip col (x16 strips of 4 px)
    const int tiy = tid >> 4;          // row (16 rows); strips at tiy and tiy+16
    const int w = w0 + 4 * tix;
    const int hA = h0 + tiy;
    const int baseA = (hA << 9) + w;
    const int baseB = baseA + (16 << 9);

    // ---- phase 1a: issue ALL global loads up front (12 outstanding) ----
    vfloat4 xa[4], xb[4];  // [class] -> 4 px each, strips A and B
    #pragma unroll
    for (int c = 0; c < 4; c++)
        xa[c] = *reinterpret_cast<const vfloat4*>(lb + (size_t)c * HW + baseA);
    #pragma unroll
    for (int c = 0; c < 4; c++)
        xb[c] = *reinterpret_cast<const vfloat4*>(lb + (size_t)c * HW + baseB);

    // border ring (196 cells) — issue loads now, consume after strip compute
    float r0 = 0.f, r1 = 0.f, r2 = 0.f, r3 = 0.f;
    int ringdst = 0;
    bool ringv = false;
    if (tid < 196) {
        int ly, lx;
        if (tid < 66)       { ly = 0;         lx = tid;       }
        else if (tid < 132) { ly = 33;        lx = tid - 66;  }
        else if (tid < 164) { ly = tid - 131; lx = 0;         }
        else                { ly = tid - 163; lx = 65;        }
        ringdst = ly * CWP + lx;
        int hh = h0 + ly - 1;
        int ww = w0 + lx - 1;
        if ((unsigned)hh < 512u && (unsigned)ww < 512u) {
            ringv = true;
            int bb = (hh << 9) + ww;
            r0 = lb[bb];
            r1 = lb[HW + bb];
            r2 = lb[2 * HW + bb];
            r3 = lb[3 * HW + bb];
        }
    }

    // per-pixel worker: argmax -> cls nibble to LDS, softmax -> 4 bins packed
    auto px_phase1 = [&](float x0, float x1, float x2, float x3,
                         int clsaddr) -> unsigned int {
        // argmax(logits) == argmax(softmax), first-index tie-break (bit-exact since R2)
        int c = 0; float best = x0;
        if (x1 > best) { best = x1; c = 1; }
        if (x2 > best) { best = x2; c = 2; }
        if (x3 > best) { best = x3; c = 3; }
        cls[clsaddr] = 1u << (4 * c);

        float m = fmaxf(fmaxf(x0, x1), fmaxf(x2, x3));
        float t0 = x0 - m, t1 = x1 - m, t2 = x2 - m, t3 = x3 - m;
        // fast path: native exp + rcp; |q_fast - q_exact| <= ~1.2e-5 << DELTA
        float f0 = __expf(t0), f1 = __expf(t1), f2 = __expf(t2), f3 = __expf(t3);
        float sf = ((f0 + f1) + f2) + f3;
        float rs = __builtin_amdgcn_rcpf(sf);
        float q[4];
        q[0] = (f0 * rs) * 15.0f; q[1] = (f1 * rs) * 15.0f;
        q[2] = (f2 * rs) * 15.0f; q[3] = (f3 * rs) * 15.0f;
        bool slow = false;
        #pragma unroll
        for (int c2 = 0; c2 < 4; c2++) {
            float fr = q[c2] - floorf(q[c2]);
            slow |= (fr < DELTA) | (fr > 1.0f - DELTA);
        }
        if (slow) {  // exact ocml-exp + IEEE-divide chain (matches np: absmax 0 in R2/R3)
            float e0 = expf(t0), e1 = expf(t1), e2 = expf(t2), e3 = expf(t3);
            float s = ((e0 + e1) + e2) + e3;
            q[0] = (e0 / s) / BWIDTH; q[1] = (e1 / s) / BWIDTH;
            q[2] = (e2 / s) / BWIDTH; q[3] = (e3 / s) / BWIDTH;
        }
        unsigned int pb = 0;
        #pragma unroll
        for (int c2 = 0; c2 < 4; c2++) {
            int bin = (int)q[c2];
            bin = bin > 14 ? 14 : bin;
            pb |= (unsigned int)bin << (4 * c2);
        }
        return pb;
    };

    unsigned int pbinA[4], pbinB[4];
    #pragma unroll
    for (int j = 0; j < 4; j++)
        pbinA[j] = px_phase1(xa[0][j], xa[1][j], xa[2][j], xa[3][j],
                             (tiy + 1) * CWP + 1 + 4 * tix + j);
    #pragma unroll
    for (int j = 0; j < 4; j++)
        pbinB[j] = px_phase1(xb[0][j], xb[1][j], xb[2][j], xb[3][j],
                             (tiy + 17) * CWP + 1 + 4 * tix + j);

    // ring argmax + LDS write (loads have had two strips of softmax to land)
    if (tid < 196) {
        unsigned int v = 0;
        if (ringv) {
            int c = 0; float best = r0;
            if (r1 > best) { best = r1; c = 1; }
            if (r2 > best) { best = r2; c = 2; }
            if (r3 > best) { best = r3; c = 3; }
            v = 1u << (4 * c);
        }
        cls[ringdst] = v;
    }
    __syncthreads();

    // ---- phase 2: neighbor counts + gather + normalize + store ----
    auto strip_phase2 = [&](int row0, const unsigned int* pbin, float* ob) {
        const unsigned int* p0 = &cls[row0 * CWP + 4 * tix];
        unsigned int r1v[6], colsum[6];
        #pragma unroll
        for (int j = 0; j < 6; j++) {
            unsigned int a    = p0[j];
            unsigned int bmid = p0[CWP + j];
            unsigned int cbot = p0[2 * CWP + j];
            r1v[j] = bmid;
            colsum[j] = a + bmid + cbot;
        }

        float res[4][4];  // [class][px]
        #pragma unroll
        for (int j = 0; j < 4; j++) {
            unsigned int pk = colsum[j] + colsum[j + 1] + colsum[j + 2] - r1v[j + 1];
            unsigned int pb = pbin[j];
            float cs = 0.0f;
            float cal[4];
            #pragma unroll
            for (int c = 0; c < 4; c++) {
                int cnt = (int)((pk >> (4 * c)) & 0xFu);   // [0,8]
                int bin = (int)((pb >> (4 * c)) & 0xFu);   // [0,14]
                float v = vf[c * 135 + cnt * 15 + bin];
                cal[c] = v;
                cs += v;                                   // ref class order
            }
            if (cs == 0.0f) cs = 1.0f;
            float inv = __builtin_amdgcn_rcpf(cs);         // tolerance 1.97e-2 >> 1 ULP
            #pragma unroll
            for (int c = 0; c < 4; c++) res[c][j] = cal[c] * inv;
        }
        #pragma unroll
        for (int c = 0; c < 4; c++) {
            vfloat4 v;
            v.x = res[c][0]; v.y = res[c][1]; v.z = res[c][2]; v.w = res[c][3];
            __builtin_nontemporal_store(v, reinterpret_cast<vfloat4*>(ob + (size_t)c * HW));
        }
    };

    float* obase = out + (size_t)b * 4 * HW;
    strip_phase2(tiy,      pbinA, obase + baseA);
    strip_phase2(tiy + 16, pbinB, obase + baseB);
}

extern "C" void kernel_launch(void* const* d_in, const int* in_sizes, int n_in,
                              void* d_out, int out_size, void* d_ws, size_t ws_size,
                              hipStream_t stream) {
    const float* logits    = (const float*)d_in[0];
    const float* val_freqs = (const float*)d_in[1];
    float* out             = (float*)d_out;

    dim3 block(256, 1, 1);
    dim3 grid(512 / TX, 512 / TY, 16);   // (8, 16, 16) = 2048 blocks
    hipLaunchKernelGGL(nectar_binning_kernel, grid, block, 0, stream,
                       logits, val_freqs, out);
}

// Round 2
// 110.928 us; speedup vs baseline: 1.0729x; 1.0729x over previous
//
#include <hip/hip_runtime.h>

#define HW (512 * 512)

typedef float vfloat4 __attribute__((ext_vector_type(4)));  // clang-native: OK for nontemporal builtins
typedef float vfloat2 __attribute__((ext_vector_type(2)));
typedef unsigned int vuint4 __attribute__((ext_vector_type(4)));

constexpr int CWP = 516;              // LDS row stride in words: 512 + 2 halo cols + 2 junk (keeps b128 16B-aligned)
constexpr float BWIDTH = 1.0f / 15.0f;
constexpr float DELTA = 3e-5f;        // guard >= ~2.5x the 1.2e-5 fast-path error bound

__global__ __launch_bounds__(512) void nectar_binning_kernel(
    const float* __restrict__ logits,      // [16,4,512,512]
    const float* __restrict__ val_freqs,   // [4,9,15]
    float* __restrict__ out)               // [16,4,512,512]
{
    // one-hot nibble pack per halo cell: 1u<<(4*class), 0 for out-of-bounds
    __shared__ unsigned int cls[6 * CWP];   // 6 rows (4 + 2 halo) x full 512-width (+2 halo cols)
    __shared__ float vf[540];

    // XCD-chunk swizzle (bijective, 2048 % 8 == 0): each XCD owns 256 consecutive
    // logical blocks -> vertically-adjacent panels share an XCD L2 -> halo rows hit L2.
    const unsigned int f = blockIdx.x;
    const unsigned int l = ((f & 7u) << 8) | (f >> 3);
    const int panel = (int)(l & 127u);     // 128 row-panels of 4 rows
    const int b     = (int)(l >> 7);       // 16 batches
    const int h0  = panel * 4;
    const int tid = (int)threadIdx.x;

    for (int i = tid; i < 540; i += 512) vf[i] = val_freqs[i];
    if (tid < 6) { cls[tid * CWP] = 0u; cls[tid * CWP + 513] = 0u; }  // left/right zero-pad cols

    const float* lb = logits + (size_t)b * 4 * HW;

    // interior: 1 strip of 4 px per thread; wave = 64 consecutive strips of one row
    const int r = tid >> 7;            // row in panel, 0..3
    const int t = tid & 127;           // strip col
    const int w = 4 * t;
    const int base = ((h0 + r) << 9) + w;

    // ---- phase 1a: issue ALL global loads up front ----
    vfloat4 xa[4];  // [class] -> 4 px
    #pragma unroll
    for (int c = 0; c < 4; c++)
        xa[c] = *reinterpret_cast<const vfloat4*>(lb + (size_t)c * HW + base);

    // halo rows (h0-1 and h0+4): 2 px per thread, fully coalesced float2 loads.
    // Issued AFTER interior so in-order vmcnt retirement lets softmax consume
    // interior loads without draining the halo.
    const int hrow = tid >> 8;         // 0 = top halo, 1 = bottom halo
    const int p = tid & 255;           // halo pixel pair index
    const int hh = hrow ? (h0 + 4) : (h0 - 1);
    const bool hv = (unsigned)hh < 512u;
    vfloat2 hx[4];
    #pragma unroll
    for (int c = 0; c < 4; c++) { hx[c].x = 0.f; hx[c].y = 0.f; }
    if (hv) {
        const int hb = (hh << 9) + 2 * p;
        #pragma unroll
        for (int c = 0; c < 4; c++)
            hx[c] = *reinterpret_cast<const vfloat2*>(lb + (size_t)c * HW + hb);
    }

    // per-pixel worker: argmax -> cls nibble to LDS, softmax -> 4 bins packed
    auto px_phase1 = [&](float x0, float x1, float x2, float x3,
                         int clsaddr) -> unsigned int {
        // argmax(logits) == argmax(softmax), first-index tie-break (bit-exact since R2)
        int c = 0; float best = x0;
        if (x1 > best) { best = x1; c = 1; }
        if (x2 > best) { best = x2; c = 2; }
        if (x3 > best) { best = x3; c = 3; }
        cls[clsaddr] = 1u << (4 * c);

        float m = fmaxf(fmaxf(x0, x1), fmaxf(x2, x3));
        float t0 = x0 - m, t1 = x1 - m, t2 = x2 - m, t3 = x3 - m;
        // fast path: native exp + rcp; |q_fast - q_exact| <= ~1.2e-5 << DELTA
        float f0 = __expf(t0), f1 = __expf(t1), f2 = __expf(t2), f3 = __expf(t3);
        float sf = ((f0 + f1) + f2) + f3;
        float rs = __builtin_amdgcn_rcpf(sf);
        float q[4];
        q[0] = (f0 * rs) * 15.0f; q[1] = (f1 * rs) * 15.0f;
        q[2] = (f2 * rs) * 15.0f; q[3] = (f3 * rs) * 15.0f;
        bool slow = false;
        #pragma unroll
        for (int c2 = 0; c2 < 4; c2++) {
            float fr = q[c2] - floorf(q[c2]);
            slow |= (fr < DELTA) | (fr > 1.0f - DELTA);
        }
        if (slow) {  // exact ocml-exp + IEEE-divide chain (matches np: absmax 0 in R2/R3)
            float e0 = expf(t0), e1 = expf(t1), e2 = expf(t2), e3 = expf(t3);
            float s = ((e0 + e1) + e2) + e3;
            q[0] = (e0 / s) / BWIDTH; q[1] = (e1 / s) / BWIDTH;
            q[2] = (e2 / s) / BWIDTH; q[3] = (e3 / s) / BWIDTH;
        }
        unsigned int pb = 0;
        #pragma unroll
        for (int c2 = 0; c2 < 4; c2++) {
            int bin = (int)q[c2];
            bin = bin > 14 ? 14 : bin;
            pb |= (unsigned int)bin << (4 * c2);
        }
        return pb;
    };

    unsigned int pbin[4];
    #pragma unroll
    for (int j = 0; j < 4; j++)
        pbin[j] = px_phase1(xa[0][j], xa[1][j], xa[2][j], xa[3][j],
                            (r + 1) * CWP + 1 + w + j);

    // halo argmax + LDS write (loads have had 4 px of softmax to land)
    {
        unsigned int v0 = 0, v1 = 0;
        if (hv) {
            int c = 0; float best = hx[0].x;
            if (hx[1].x > best) { best = hx[1].x; c = 1; }
            if (hx[2].x > best) { best = hx[2].x; c = 2; }
            if (hx[3].x > best) { best = hx[3].x; c = 3; }
            v0 = 1u << (4 * c);
            c = 0; best = hx[0].y;
            if (hx[1].y > best) { best = hx[1].y; c = 1; }
            if (hx[2].y > best) { best = hx[2].y; c = 2; }
            if (hx[3].y > best) { best = hx[3].y; c = 3; }
            v1 = 1u << (4 * c);
        }
        const int hl = hrow * 5 * CWP + 1 + 2 * p;   // LDS rows 0 and 5
        cls[hl]     = v0;
        cls[hl + 1] = v1;
    }
    __syncthreads();

    // ---- phase 2: neighbor counts + gather + normalize + store ----
    // rows r..r+2 (LDS), words 516*row + 4t: 16B-aligned -> 2x ds_read_b128 per row,
    // 64 lanes x 4 consecutive words = exactly 8 words/bank -> conflict-free.
    const unsigned int* p0 = &cls[r * CWP + w];
    vuint4 ra[3], rb[3];
    #pragma unroll
    for (int k = 0; k < 3; k++) {
        ra[k] = *reinterpret_cast<const vuint4*>(p0 + k * CWP);
        rb[k] = *reinterpret_cast<const vuint4*>(p0 + k * CWP + 4);
    }
    unsigned int colsum[6], mid[6];
    #pragma unroll
    for (int k = 0; k < 6; k++) {
        unsigned int a0 = (k < 4) ? ra[0][k] : rb[0][k - 4];
        unsigned int a1 = (k < 4) ? ra[1][k] : rb[1][k - 4];
        unsigned int a2 = (k < 4) ? ra[2][k] : rb[2][k - 4];
        mid[k] = a1;
        colsum[k] = a0 + a1 + a2;
    }

    float res[4][4];  // [class][px]
    #pragma unroll
    for (int j = 0; j < 4; j++) {
        unsigned int pk = colsum[j] + colsum[j + 1] + colsum[j + 2] - mid[j + 1];
        unsigned int pb = pbin[j];
        float cs = 0.0f;
        float cal[4];
        #pragma unroll
        for (int c = 0; c < 4; c++) {
            int cnt = (int)((pk >> (4 * c)) & 0xFu);   // [0,8]
            int bin = (int)((pb >> (4 * c)) & 0xFu);   // [0,14]
            float v = vf[c * 135 + cnt * 15 + bin];
            cal[c] = v;
            cs += v;                                   // ref class order
        }
        if (cs == 0.0f) cs = 1.0f;
        float inv = __builtin_amdgcn_rcpf(cs);         // tolerance 1.97e-2 >> 1 ULP
        #pragma unroll
        for (int c = 0; c < 4; c++) res[c][j] = cal[c] * inv;
    }

    float* ob = out + (size_t)b * 4 * HW + base;
    #pragma unroll
    for (int c = 0; c < 4; c++) {
        vfloat4 v;
        v.x = res[c][0]; v.y = res[c][1]; v.z = res[c][2]; v.w = res[c][3];
        __builtin_nontemporal_store(v, reinterpret_cast<vfloat4*>(ob + (size_t)c * HW));
    }
}

extern "C" void kernel_launch(void* const* d_in, const int* in_sizes, int n_in,
                              void* d_out, int out_size, void* d_ws, size_t ws_size,
                              hipStream_t stream) {
    const float* logits    = (const float*)d_in[0];
    const float* val_freqs = (const float*)d_in[1];
    float* out             = (float*)d_out;

    dim3 block(512, 1, 1);
    dim3 grid(2048, 1, 1);   // 128 row-panels x 16 batches, XCD-swizzled in-kernel
    hipLaunchKernelGGL(nectar_binning_kernel, grid, block, 0, stream,
                       logits, val_freqs, out);
}